// Round 3
// 616.110 us; speedup vs baseline: 1.0180x; 1.0180x over previous
//
#include <hip/hip_runtime.h>

// Problem constants (match reference)
#define NROWS     64
#define NTHREADS  1024        // 16 waves -> 4 waves/SIMD (was 8 waves -> 2/SIMD)
#define DEEP_IN   164         // 64 user + 64 item + 32 cat + 2 price + 2 temporal
#define NCHUNK    41          // DEEP_IN / 4 float4 chunks
#define XS_STRIDE 192         // floats per xs row = 48 chunks (swizzle kc^7 <= 47)
#define H1        128
#define H2        64
#define H3        32
#define DIM2_C    10000

// LDS arena (floats) - no aliasing, one fewer barrier:
#define XS_OFF  0                          // 64 x 192 swizzled chunks = 12288
#define H1_OFF  (NROWS * XS_STRIDE)        // 12288, 64 x 128 = 8192
#define H2_OFF  (H1_OFF + NROWS * H1)      // 20480, 64 x 64  = 4096
#define H3_OFF  (H2_OFF + NROWS * H2)      // 24576, 64 x 32  = 2048
#define WD_OFF  (H3_OFF + NROWS * H3)      // 26624, 64
#define ARENA_F (WD_OFF + NROWS)           // 26688 floats = 106752 B < 160 KiB

__global__ __launch_bounds__(NTHREADS) void wad_fused(
    const float* __restrict__ user, const float* __restrict__ price,
    const float* __restrict__ temporal, const float* __restrict__ item_emb,
    const float* __restrict__ cat_emb, const float* __restrict__ we1,
    const float* __restrict__ we2, const float* __restrict__ crossW,
    const int* __restrict__ item_ids, const int* __restrict__ cat_ids,
    const int* __restrict__ wf1, const int* __restrict__ wf2,
    const float* __restrict__ W1, const float* __restrict__ b1,
    const float* __restrict__ W2, const float* __restrict__ b2,
    const float* __restrict__ W3, const float* __restrict__ b3,
    const float* __restrict__ W4, const float* __restrict__ b4,
    const float* __restrict__ g1, const float* __restrict__ be1,
    const float* __restrict__ g2, const float* __restrict__ be2,
    const float* __restrict__ g3, const float* __restrict__ be3,
    float* __restrict__ out)
{
    __shared__ float arena[ARENA_F];
    float* xs    = arena + XS_OFF;
    float* h1s   = arena + H1_OFF;
    float* h2s   = arena + H2_OFF;
    float* h3s   = arena + H3_OFF;
    float* wideS = arena + WD_OFF;

    const int tid  = threadIdx.x;
    const int lane = tid & 63;
    const int wave = tid >> 6;
    const int lx   = lane & 7;
    const int r0   = blockIdx.x * NROWS;

    const float bn_rs = rsqrtf(1.0f + 1e-5f);

    // ---------------- phase 0: float4 gather of X tile (swizzled) + wide ----------------
    for (int idx = tid; idx < NROWS * NCHUNK; idx += NTHREADS) {
        int r  = idx / NCHUNK;
        int k4 = idx - r * NCHUNK;
        int R  = r0 + r;
        float4 v;
        if (k4 < 16)      v = *(const float4*)(user + R * 64 + k4 * 4);
        else if (k4 < 32) v = *(const float4*)(item_emb + item_ids[R] * 64 + (k4 - 16) * 4);
        else if (k4 < 40) v = *(const float4*)(cat_emb + cat_ids[R] * 32 + (k4 - 32) * 4);
        else {            // k4 == 40: {price0, price1, temporal0, temporal1}
            float2 p = *(const float2*)(price + R * 2);
            float2 t = *(const float2*)(temporal + R * 2);
            v = make_float4(p.x, p.y, t.x, t.y);
        }
        int kcs = k4 ^ (r & 7);                       // XOR swizzle, 0..47 < 48
        *(float4*)(xs + r * XS_STRIDE + kcs * 4) = v;
    }
    if (tid < NROWS) {
        int R = r0 + tid;
        int f1 = wf1[R], f2 = wf2[R];
        wideS[tid] = we1[f1] + we2[f2] + crossW[f1 * DIM2_C + f2];
    }
    __syncthreads();

    // ---------------- layer 1: [164] -> [128], lane=row, wave owns 8 cols ----------------
    {
        const int c0 = __builtin_amdgcn_readfirstlane(wave * 8);
        float acc[8];
#pragma unroll
        for (int n = 0; n < 8; ++n) acc[n] = 0.0f;
        const float* xrow = xs + lane * XS_STRIDE;
        for (int kq = 0; kq < NCHUNK; ++kq) {
            float4 a = *(const float4*)(xrow + (kq ^ lx) * 4);   // conflict-free swizzled
            const float* wbase = W1 + kq * 4 * H1 + c0;          // wave-uniform
#pragma unroll
            for (int kk = 0; kk < 4; ++kk) {
                float av = ((const float*)&a)[kk];
#pragma unroll
                for (int n = 0; n < 8; ++n) acc[n] += av * wbase[kk * H1 + n];
            }
        }
        // epilogue: bias + eval-BN + relu, store swizzled h1s (no alias -> no pre-barrier)
#pragma unroll
        for (int n = 0; n < 8; n += 4) {
            float4 o;
#pragma unroll
            for (int e = 0; e < 4; ++e) {
                int c = c0 + n + e;
                float z = (acc[n + e] + b1[c]) * (g1[c] * bn_rs) + be1[c];
                ((float*)&o)[e] = fmaxf(z, 0.0f);
            }
            int kc  = (c0 + n) >> 2;                  // chunk 0..31
            int kcs = kc ^ lx;
            *(float4*)(h1s + lane * H1 + kcs * 4) = o;
        }
    }
    __syncthreads();

    // ---------------- layer 2: [128] -> [64], wave owns 4 cols ----------------
    {
        const int c02 = __builtin_amdgcn_readfirstlane(wave * 4);
        float acc2[4];
#pragma unroll
        for (int n = 0; n < 4; ++n) acc2[n] = 0.0f;
        for (int kq = 0; kq < H1 / 4; ++kq) {
            float4 a = *(const float4*)(h1s + lane * H1 + (kq ^ lx) * 4);
            const float* wbase = W2 + kq * 4 * H2 + c02;
#pragma unroll
            for (int kk = 0; kk < 4; ++kk) {
                float av = ((const float*)&a)[kk];
#pragma unroll
                for (int n = 0; n < 4; ++n) acc2[n] += av * wbase[kk * H2 + n];
            }
        }
        float4 o;
#pragma unroll
        for (int e = 0; e < 4; ++e) {
            int c = c02 + e;
            float z = (acc2[e] + b2[c]) * (g2[c] * bn_rs) + be2[c];
            ((float*)&o)[e] = fmaxf(z, 0.0f);
        }
        int kcs = wave ^ lx;                           // chunk idx == wave, 0..15
        *(float4*)(h2s + lane * H2 + kcs * 4) = o;
    }
    __syncthreads();

    // ---------------- layer 3: [64] -> [32], wave owns 2 cols ----------------
    {
        const int c03 = __builtin_amdgcn_readfirstlane(wave * 2);
        float acc3[2];
        acc3[0] = 0.0f; acc3[1] = 0.0f;
        for (int kq = 0; kq < H2 / 4; ++kq) {
            float4 a = *(const float4*)(h2s + lane * H2 + (kq ^ lx) * 4);
            const float* wbase = W3 + kq * 4 * H3 + c03;
#pragma unroll
            for (int kk = 0; kk < 4; ++kk) {
                float av = ((const float*)&a)[kk];
                acc3[0] += av * wbase[kk * H3];
                acc3[1] += av * wbase[kk * H3 + 1];
            }
        }
        float2 o;
        {
            int c = c03;
            float z0 = (acc3[0] + b3[c]) * (g3[c] * bn_rs) + be3[c];
            float z1 = (acc3[1] + b3[c + 1]) * (g3[c + 1] * bn_rs) + be3[c + 1];
            o.x = fmaxf(z0, 0.0f);
            o.y = fmaxf(z1, 0.0f);
        }
        int ps = wave ^ (lane & 15);                   // pair idx 0..15, bijective per lane
        *(float2*)(h3s + lane * H3 + ps * 2) = o;
    }
    __syncthreads();

    // ---------------- layer 4 + wide: [32] -> [1] ----------------
    if (tid < NROWS) {
        int j = tid;
        float s = b4[0];
#pragma unroll
        for (int w = 0; w < 16; ++w) {
            int ps = w ^ (j & 15);                     // where wave w's pair landed
            float2 h = *(const float2*)(h3s + j * H3 + ps * 2);
            s += h.x * W4[2 * w] + h.y * W4[2 * w + 1];
        }
        out[r0 + j] = s + wideS[j];
    }
}

extern "C" void kernel_launch(void* const* d_in, const int* in_sizes, int n_in,
                              void* d_out, int out_size, void* d_ws, size_t ws_size,
                              hipStream_t stream) {
    const float* user     = (const float*)d_in[0];
    const float* price    = (const float*)d_in[1];
    const float* temporal = (const float*)d_in[2];
    const float* item_emb = (const float*)d_in[3];
    const float* cat_emb  = (const float*)d_in[4];
    const float* we1      = (const float*)d_in[5];
    const float* we2      = (const float*)d_in[6];
    const float* crossW   = (const float*)d_in[7];
    const int*   item_ids = (const int*)d_in[8];
    const int*   cat_ids  = (const int*)d_in[9];
    const int*   wf1      = (const int*)d_in[10];
    const int*   wf2      = (const int*)d_in[11];
    const float* W1 = (const float*)d_in[12];
    const float* b1 = (const float*)d_in[13];
    const float* W2 = (const float*)d_in[14];
    const float* b2 = (const float*)d_in[15];
    const float* W3 = (const float*)d_in[16];
    const float* b3 = (const float*)d_in[17];
    const float* W4 = (const float*)d_in[18];
    const float* b4 = (const float*)d_in[19];
    const float* g1  = (const float*)d_in[20];
    const float* be1 = (const float*)d_in[21];
    const float* g2  = (const float*)d_in[22];
    const float* be2 = (const float*)d_in[23];
    const float* g3  = (const float*)d_in[24];
    const float* be3 = (const float*)d_in[25];
    float* out = (float*)d_out;

    const int nblocks = 16384 / NROWS;   // 256 blocks = 1 per CU, 16 waves each
    wad_fused<<<nblocks, NTHREADS, 0, stream>>>(
        user, price, temporal, item_emb, cat_emb, we1, we2, crossW,
        item_ids, cat_ids, wf1, wf2,
        W1, b1, W2, b2, W3, b3, W4, b4,
        g1, be1, g2, be2, g3, be3, out);
}